// Round 8
// baseline (343.332 us; speedup 1.0000x reference)
//
#include <hip/hip_runtime.h>
#include <cstdint>
#include <cstddef>

#define BB 32
#define EV 5
#define LL 130
#define HH 768
#define KK 21
#define LP 160    // score row stride (padded)
#define SD 136    // compact Sg col count (d < 136)
#define SR 130    // compact Sg row count

typedef __attribute__((ext_vector_type(8))) __bf16 bf16x8;
typedef __attribute__((ext_vector_type(4))) float f32x4;

__device__ __forceinline__ unsigned short f2bf(float f) {
    unsigned int u = __float_as_uint(f);
    u += 0x7FFFu + ((u >> 16) & 1u);   // RNE: keeps ||hn||^2 = 1 +- ~1e-4 (sigma=0.001 kernel!)
    return (unsigned short)(u >> 16);
}
__device__ __forceinline__ float bf2f(unsigned int s) {
    return __uint_as_float(s << 16);
}

// ---------------------------------------------------------------------------
// K1 (merged prologue):
//   blocks [0,5200):     L2-normalize hiddens rows -> bf16 (130 rows per n)
//   blocks [5200,5968):  Wg1 -> bf16
//   blocks [5968,6768):  Xg pooled half
//   blocks [6768,6868):  zero cg (replaces hipMemsetAsync dispatch)
// ---------------------------------------------------------------------------
__global__ __launch_bounds__(256) void k_prologue(const float* __restrict__ hid,
        unsigned short* __restrict__ hnbf, const float* __restrict__ wg1,
        unsigned short* __restrict__ wg1b, const float* __restrict__ pooled,
        unsigned short* __restrict__ xg, float* __restrict__ cg) {
    int bid = blockIdx.x, tid = threadIdx.x;
    if (bid < 5200) {
        int wave = tid >> 6, lane = tid & 63;
        int r = bid * 4 + wave;          // 0 .. 20800
        if (r >= 160 * LL) return;
        const float4* s4 = (const float4*)(hid + (size_t)r * HH);
        float4 v0 = s4[lane], v1 = s4[lane + 64], v2 = s4[lane + 128];
        float ss = v0.x*v0.x + v0.y*v0.y + v0.z*v0.z + v0.w*v0.w
                 + v1.x*v1.x + v1.y*v1.y + v1.z*v1.z + v1.w*v1.w
                 + v2.x*v2.x + v2.y*v2.y + v2.z*v2.z + v2.w*v2.w;
        #pragma unroll
        for (int m = 1; m < 64; m <<= 1) ss += __shfl_xor(ss, m, 64);
        float sc = 1.0f / fmaxf(sqrtf(ss), 1e-12f);
        ushort4 o0, o1, o2;
        o0.x = f2bf(v0.x*sc); o0.y = f2bf(v0.y*sc); o0.z = f2bf(v0.z*sc); o0.w = f2bf(v0.w*sc);
        o1.x = f2bf(v1.x*sc); o1.y = f2bf(v1.y*sc); o1.z = f2bf(v1.z*sc); o1.w = f2bf(v1.w*sc);
        o2.x = f2bf(v2.x*sc); o2.y = f2bf(v2.y*sc); o2.z = f2bf(v2.z*sc); o2.w = f2bf(v2.w*sc);
        ushort4* d4 = (ushort4*)(hnbf + (size_t)r * HH);
        d4[lane] = o0; d4[lane + 64] = o1; d4[lane + 128] = o2;
    } else if (bid < 5968) {
        int idx = (bid - 5200) * 256 + tid;      // < 196608 exactly
        wg1b[idx] = f2bf(wg1[idx]);
    } else if (bid < 6768) {
        int row = bid - 5968;                    // 0..799
        int bi = row / 5;
        const float* src = pooled + (size_t)bi * HH;
        unsigned short* dst = xg + (size_t)row * 1536;
        #pragma unroll
        for (int j = 0; j < 3; j++) { int h = tid + j * 256; dst[h] = f2bf(src[h]); }
    } else {
        int slot = (bid - 6768) * 256 + tid;     // 100*256 slots x 4 floats = 102400
        float4 z = (float4){0.f, 0.f, 0.f, 0.f};
        *(float4*)&cg[(size_t)slot * 4] = z;
    }
}

// ---------------------------------------------------------------------------
// K2: batched similarity GEMM. Single-barrier double-buffered LDS, BK=32.
// Per k-step: prefetch k+1 global->reg (overlaps MFMA), ds_read+MFMA from
// buf[cur], ds_write regs->buf[1-cur], ONE barrier.
// Bank-conflict-free XOR: LDS seg q of row r holds global seg q^((r>>1)&3);
// read seg = quad^((row>>1)&3) -> bank base 16*(row&1)+4*seg: each 4-bank
// span hit by exactly 2 lanes (free, m136). Writes are stride-1 (free).
// 800 blocks; xcd = bid&7 owns b in [4*xcd, 4*xcd+4) for L2 locality.
// ---------------------------------------------------------------------------
__global__ __launch_bounds__(256) void k_sim_gemm(const unsigned short* __restrict__ hnbf,
                                                  unsigned short* __restrict__ Sg) {
    int w = blockIdx.x;
    int xcd = w & 7, slot = w >> 3;            // 800 = 8*100
    int b = xcd * 4 + (slot / 25);
    int ei = slot % 25;
    int e = ei / 5, i = ei % 5;
    int pair = b * 25 + ei;
    const unsigned short* A = hnbf + (size_t)(b * 5 + e) * LL * HH;
    const unsigned short* B = hnbf + (size_t)(b * 5 + i) * LL * HH;
    __shared__ unsigned short As[2][160 * 32];
    __shared__ unsigned short Bs[2][160 * 32];
    int tid = threadIdx.x, lane = tid & 63, wave = tid >> 6;
    int quad = lane >> 4, l16 = lane & 15;
    int wm = (wave & 1) * 5, wn = (wave >> 1) * 5;

    // staging: slot s in [0,640): row r=s>>2; LDS seg s&3 (at s*8 shorts)
    // holds global seg (s&3)^((r>>1)&3) of row r.
    int goff[3];
    #pragma unroll
    for (int it = 0; it < 3; it++) {
        int s = tid + it * 256;
        int r = s >> 2;
        int rs = (r < LL) ? r : 0;              // clamp: finite junk, masked later
        goff[it] = rs * HH + (((s & 3) ^ ((r >> 1) & 3)) * 8);
    }
    // per-wave LDS read offsets (shorts), constant over the k-loop
    int rdA[5], rdB[5];
    #pragma unroll
    for (int t = 0; t < 5; t++) {
        int ra = (wm + t) * 16 + l16;
        int rb = (wn + t) * 16 + l16;
        rdA[t] = ra * 32 + (quad ^ ((ra >> 1) & 3)) * 8;
        rdB[t] = rb * 32 + (quad ^ ((rb >> 1) & 3)) * 8;
    }

    uint4 rga[3], rgb[3];
    auto LOADK = [&](int k0) {
        #pragma unroll
        for (int it = 0; it < 3; it++) {
            int s = tid + it * 256;
            if (s < 640) {
                rga[it] = *(const uint4*)(A + goff[it] + k0);
                rgb[it] = *(const uint4*)(B + goff[it] + k0);
            }
        }
    };
    auto STOREB = [&](int buf) {
        #pragma unroll
        for (int it = 0; it < 3; it++) {
            int s = tid + it * 256;
            if (s < 640) {
                *(uint4*)&As[buf][s * 8] = rga[it];
                *(uint4*)&Bs[buf][s * 8] = rgb[it];
            }
        }
    };

    f32x4 acc[5][5];
    #pragma unroll
    for (int mt = 0; mt < 5; mt++)
        #pragma unroll
        for (int nt = 0; nt < 5; nt++) acc[mt][nt] = (f32x4){0.f, 0.f, 0.f, 0.f};

    LOADK(0);
    STOREB(0);
    __syncthreads();
    for (int ks = 0; ks < 24; ks++) {
        int cur = ks & 1;
        if (ks < 23) LOADK((ks + 1) * 32);
        bf16x8 af[5], bfr[5];
        #pragma unroll
        for (int t = 0; t < 5; t++) {
            af[t]  = *(const bf16x8*)&As[cur][rdA[t]];
            bfr[t] = *(const bf16x8*)&Bs[cur][rdB[t]];
        }
        #pragma unroll
        for (int mt = 0; mt < 5; mt++)
            #pragma unroll
            for (int nt = 0; nt < 5; nt++)
                acc[mt][nt] = __builtin_amdgcn_mfma_f32_16x16x32_bf16(af[mt], bfr[nt], acc[mt][nt], 0, 0, 0);
        if (ks < 23) STOREB(cur ^ 1);
        __syncthreads();
    }

    size_t base = (size_t)pair * SR * SD;
    #pragma unroll
    for (int mt = 0; mt < 5; mt++)
        #pragma unroll
        for (int nt = 0; nt < 5; nt++) {
            int R0 = (wm + mt) * 16 + quad * 4;
            int C = (wn + nt) * 16 + l16;
            if (C < SD) {
                #pragma unroll
                for (int reg = 0; reg < 4; reg++) {
                    int R = R0 + reg;
                    if (R < SR) Sg[base + (size_t)R * SD + C] = f2bf(acc[mt][nt][reg]);
                }
            }
        }
}

// ---------------------------------------------------------------------------
// K3: kernel-pool. grid 4000, XCD-swizzled to match k_sim_gemm's b placement.
// 26 rows per block, 8 lanes per row streaming 16B uint4 from compact Sg.
// Gaussian-grid trick: exp(-50(s-mu_k)^2) = C_k * u * r^(k-1),
//   u=exp(-50 s^2+95 s), r=exp(-10 s), C_k=exp(-50 mu_k^2); k=0 direct.
// ---------------------------------------------------------------------------
template <bool DIAG>
__device__ __forceinline__ void pool_body(
    int pair, int row, int lane8, bool live, int ne, int c,
    const unsigned short* __restrict__ Sg,
    const float* __restrict__ batt,
    float* __restrict__ score, float* __restrict__ selp, float* __restrict__ denp,
    const float* wdA, const float* wdE, const float* wqC,
    const float* WaL, const float* WsL, const float* CkL,
    float* redsel, float* redden) {

    const float LOG2E = 1.4426950408889634f;
    const float CA = -50.0f * LOG2E;
    const float CB = 95.0f * LOG2E;
    const float CR = -10.0f * LOG2E;
    const float C0 = -500000.0f * LOG2E;
    int tid = threadIdx.x;

    float a0[KK], a2[KK];
    #pragma unroll
    for (int k = 0; k < KK; k++) { a0[k] = 0.0f; a2[k] = 0.0f; }

    auto proc = [&](float s, int d) {
        float w = wdA[d];
        float w2 = DIAG ? wdE[d] : 0.0f;
        float pe = exp2f(fmaf(CB, s, CA * s * s));
        float rr = exp2f(CR * s);
        float sm1 = s - 1.0f;
        float e0 = exp2f(C0 * (sm1 * sm1));
        a0[0] = fmaf(w, e0, a0[0]);
        if (DIAG) a2[0] = fmaf(w2, e0, a2[0]);
        float p = pe;
        #pragma unroll
        for (int k = 1; k < KK; k++) {
            a0[k] = fmaf(w, p, a0[k]);
            if (DIAG) a2[k] = fmaf(w2, p, a2[k]);
            p *= rr;
        }
    };

    if (live) {
        const unsigned short* Srow = Sg + (size_t)pair * SR * SD + (size_t)row * SD;
        #pragma unroll
        for (int j = 0; j < 2; j++) {
            uint4 v = *(const uint4*)(Srow + lane8 * 8 + j * 64);
            int d0 = lane8 * 8 + j * 64;
            proc(bf2f(v.x & 0xFFFFu), d0 + 0); proc(bf2f(v.x >> 16), d0 + 1);
            proc(bf2f(v.y & 0xFFFFu), d0 + 2); proc(bf2f(v.y >> 16), d0 + 3);
            proc(bf2f(v.z & 0xFFFFu), d0 + 4); proc(bf2f(v.z >> 16), d0 + 5);
            proc(bf2f(v.w & 0xFFFFu), d0 + 6); proc(bf2f(v.w >> 16), d0 + 7);
        }
        proc(bf2f((unsigned int)Srow[128 + lane8]), 128 + lane8);  // d in [128,136)
    }
    #pragma unroll
    for (int k = 0; k < KK; k++) {
        a0[k] += __shfl_xor(a0[k], 1, 64);
        a0[k] += __shfl_xor(a0[k], 2, 64);
        a0[k] += __shfl_xor(a0[k], 4, 64);
        if (DIAG) {
            a2[k] += __shfl_xor(a2[k], 1, 64);
            a2[k] += __shfl_xor(a2[k], 2, 64);
            a2[k] += __shfl_xor(a2[k], 4, 64);
        }
    }
    float selv = 0.0f, denv = 0.0f;
    if (live && lane8 == 0) {
        float sc = batt[0];
        #pragma unroll
        for (int k = 0; k < KK; k++)
            sc += WaL[k] * __logf(fmaxf(CkL[k] * a0[k], 1e-10f));
        score[(size_t)pair * LP + row] = sc;
        if (DIAG) {
            float cq = 0.0f;
            #pragma unroll
            for (int k = 0; k < KK; k++)
                cq += WsL[k] * __logf(fmaxf(CkL[k] * a2[k], 1e-10f));
            selv = wqC[row] * cq;
            denv = wqC[row];
        }
    }
    if (DIAG) {
        #pragma unroll
        for (int m = 8; m < 64; m <<= 1) {
            selv += __shfl_xor(selv, m, 64);
            denv += __shfl_xor(denv, m, 64);
        }
        int wave = tid >> 6, lane = tid & 63;
        if (lane == 0) { redsel[wave] = selv; redden[wave] = denv; }
        __syncthreads();
        if (tid == 0) {
            selp[ne * 5 + c] = redsel[0] + redsel[1] + redsel[2] + redsel[3];
            denp[ne * 5 + c] = redden[0] + redden[1] + redden[2] + redden[3];
        }
    }
}

__global__ __launch_bounds__(256) void k_pool(const unsigned short* __restrict__ Sg,
        const int* __restrict__ msk, const int* __restrict__ seg,
        const float* __restrict__ Watt, const float* __restrict__ batt,
        const float* __restrict__ Wsel,
        float* __restrict__ score, float* __restrict__ selp, float* __restrict__ denp) {
    __shared__ float wdA[SD], wdE[SD], wqC[SD];
    __shared__ float WaL[KK], WsL[KK], CkL[KK];
    __shared__ float redsel[4], redden[4];
    int w = blockIdx.x;                       // 4000 = 8 * 500
    int xcd = w & 7, slot = w >> 3;
    int b = xcd * 4 + (slot / 125);
    int rem = slot % 125;
    int ei = rem / 5, c = rem % 5;
    int e = ei / 5, i = ei % 5;
    int pair = b * 25 + ei;
    int ne = b * 5 + e, ni = b * 5 + i;
    int tid = threadIdx.x;

    if (tid < SD) {
        int d = tid;
        wdA[d] = (d >= 1 && d < LL) ? (float)msk[ni * LL + d] : 0.0f;
        float mtE = (d >= 1 && d < LL) ? (float)msk[ne * LL + d] : 0.0f;
        float sgE = (d < LL) ? (float)seg[ne * LL + d] : 0.0f;
        wdE[d] = sgE * mtE;
        wqC[d] = (1.0f - sgE) * mtE;
    }
    if (tid < KK) {
        const float LOG2E = 1.4426950408889634f;
        WaL[tid] = Watt[tid];
        WsL[tid] = Wsel[tid];
        float mu = 0.95f - 0.1f * (tid - 1);
        CkL[tid] = (tid == 0) ? 1.0f : exp2f(-50.0f * LOG2E * mu * mu);
    }
    __syncthreads();

    int row = c * 26 + (tid >> 3);
    int lane8 = tid & 7;
    bool live = (tid < 208);               // 26 rows * 8 lanes

    if (e == i)
        pool_body<true>(pair, row, lane8, live, ne, c, Sg, batt, score, selp, denp,
                        wdA, wdE, wqC, WaL, WsL, CkL, redsel, redden);
    else
        pool_body<false>(pair, row, lane8, live, ne, c, Sg, batt, score, selp, denp,
                         wdA, wdE, wqC, WaL, WsL, CkL, redsel, redden);
}

// ---------------------------------------------------------------------------
// K4 (fused att+den): grid 480 (be, j). Phase 1: waves compute the 5 masked
// softmaxes into LDS (wave w handles i = w, w+4). Phase 2: denoise chunk j.
// ---------------------------------------------------------------------------
__global__ __launch_bounds__(256) void k_attden(const float* __restrict__ score,
        const int* __restrict__ msk, const float* __restrict__ hid,
        float* __restrict__ dn, unsigned short* __restrict__ xg) {
    int bid = blockIdx.x;
    int be = bid / 3, j = bid % 3;
    int b = be / 5, e = be % 5;
    int tid = threadIdx.x, lane = tid & 63, wave = tid >> 6;
    __shared__ float attl[5 * 132];

    for (int i = wave; i < 5; i += 4) {
        const float* srow = score + ((size_t)(b * 5 + i) * 5 + e) * LP;
        float v0, v1, v2 = -1e30f;
        {
            int q = lane;
            bool mt = (q >= 1 && msk[be * LL + q] != 0);
            v0 = mt ? srow[q] : -1e4f;
        }
        {
            int q = lane + 64;
            bool mt = (msk[be * LL + q] != 0);
            v1 = mt ? srow[q] : -1e4f;
        }
        if (lane < 2) {
            int q = lane + 128;
            bool mt = (msk[be * LL + q] != 0);
            v2 = mt ? srow[q] : -1e4f;
        }
        float mx = fmaxf(v0, fmaxf(v1, v2));
        #pragma unroll
        for (int m = 1; m < 64; m <<= 1) mx = fmaxf(mx, __shfl_xor(mx, m, 64));
        float e0 = __expf(v0 - mx), e1 = __expf(v1 - mx);
        float e2 = (lane < 2) ? __expf(v2 - mx) : 0.0f;
        float Z = e0 + e1 + e2;
        #pragma unroll
        for (int m = 1; m < 64; m <<= 1) Z += __shfl_xor(Z, m, 64);
        float iz = 1.0f / Z;
        attl[i * 132 + lane] = e0 * iz;
        attl[i * 132 + lane + 64] = e1 * iz;
        if (lane < 2) attl[i * 132 + lane + 128] = e2 * iz;
    }
    __syncthreads();

    int h = j * 256 + tid;
    float accA[5] = {0.f, 0.f, 0.f, 0.f, 0.f};
    float accB[5] = {0.f, 0.f, 0.f, 0.f, 0.f};
    const float* hb = hid + (size_t)be * LL * HH + h;
    int q = 0;
    #pragma unroll 2
    for (; q + 4 <= LL; q += 4) {
        float h0 = hb[(size_t)(q + 0) * HH];
        float h1 = hb[(size_t)(q + 1) * HH];
        float h2 = hb[(size_t)(q + 2) * HH];
        float h3 = hb[(size_t)(q + 3) * HH];
        #pragma unroll
        for (int i = 0; i < 5; i++) {
            accA[i] = fmaf(attl[i * 132 + q], h0, accA[i]);
            accB[i] = fmaf(attl[i * 132 + q + 1], h1, accB[i]);
            accA[i] = fmaf(attl[i * 132 + q + 2], h2, accA[i]);
            accB[i] = fmaf(attl[i * 132 + q + 3], h3, accB[i]);
        }
    }
    for (; q < LL; q++) {
        float hv = hb[(size_t)q * HH];
        #pragma unroll
        for (int i = 0; i < 5; i++) accA[i] = fmaf(attl[i * 132 + q], hv, accA[i]);
    }
    #pragma unroll
    for (int i = 0; i < 5; i++) {
        float v = accA[i] + accB[i];
        dn[((size_t)be * 5 + i) * HH + h] = v;
        xg[((size_t)(b * 5 + i) * 5 + e) * 1536 + HH + h] = f2bf(v);
    }
}

// ---------------------------------------------------------------------------
// K5: gating GEMM Cg[800][128] += Xg[800][1536] @ Wg1^T, 3-way K-split,
// f32 atomics into prologue-zeroed cg. grid 150: bid = rb*3 + ks.
// ---------------------------------------------------------------------------
__global__ __launch_bounds__(256) void k_gate_gemm(const unsigned short* __restrict__ xg,
        const unsigned short* __restrict__ wg1b, float* __restrict__ cg) {
    int bid = blockIdx.x;
    int rb = bid / 3, ks = bid % 3;
    int m0 = rb * 16;
    __shared__ unsigned short As[16 * 32];
    __shared__ unsigned short Bs[128 * 32];
    int tid = threadIdx.x, lane = tid & 63, wave = tid >> 6;
    int quad = lane >> 4, l16 = lane & 15;
    f32x4 acc[2];
    acc[0] = (f32x4){0.f, 0.f, 0.f, 0.f};
    acc[1] = (f32x4){0.f, 0.f, 0.f, 0.f};

    for (int t = 0; t < 16; t++) {
        int k0 = ks * 512 + t * 32;
        if (tid < 64) {
            int row = tid >> 2, sg = tid & 3;
            *(uint4*)&As[tid * 8] = *(const uint4*)(xg + (size_t)(m0 + row) * 1536 + k0 + sg * 8);
        }
        #pragma unroll
        for (int it = 0; it < 2; it++) {
            int s = tid + it * 256;
            int row = s >> 2, sg = s & 3;
            *(uint4*)&Bs[s * 8] = *(const uint4*)(wg1b + (size_t)row * 1536 + k0 + sg * 8);
        }
        __syncthreads();
        bf16x8 af = *(const bf16x8*)&As[l16 * 32 + quad * 8];
        #pragma unroll
        for (int nt = 0; nt < 2; nt++) {
            int ct = wave * 2 + nt;
            bf16x8 bfr = *(const bf16x8*)&Bs[(ct * 16 + l16) * 32 + quad * 8];
            acc[nt] = __builtin_amdgcn_mfma_f32_16x16x32_bf16(af, bfr, acc[nt], 0, 0, 0);
        }
        __syncthreads();
    }
    #pragma unroll
    for (int nt = 0; nt < 2; nt++) {
        int C = (wave * 2 + nt) * 16 + l16;
        #pragma unroll
        for (int reg = 0; reg < 4; reg++) {
            int R = m0 + quad * 4 + reg;
            atomicAdd(&cg[(size_t)R * 128 + C], acc[nt][reg]);
        }
    }
}

// ---------------------------------------------------------------------------
// K6: per (b,i): g[e] = Wg2.relu(cg+bg1)+bg2; softmax_e; de; feat = Wd.concat
// ---------------------------------------------------------------------------
__global__ __launch_bounds__(256) void k_gate_epi(const float* __restrict__ cg,
        const float* __restrict__ bg1, const float* __restrict__ wg2,
        const float* __restrict__ bg2, const float* __restrict__ dn,
        const float* __restrict__ pooled, const float* __restrict__ wd,
        const float* __restrict__ bd, float* __restrict__ feat) {
    int bi = blockIdx.x;                 // b*5+i
    int b = bi / 5, ii = bi % 5;
    __shared__ float red4[4];
    __shared__ float gL[5];
    __shared__ float deL[HH];
    int tid = threadIdx.x, lane = tid & 63, wave = tid >> 6;

    for (int e = 0; e < 5; e++) {
        float v = 0.0f;
        if (tid < 128) {
            float ccv = cg[(size_t)(bi * 5 + e) * 128 + tid] + bg1[tid];
            v = wg2[tid] * fmaxf(ccv, 0.0f);
        }
        #pragma unroll
        for (int m = 1; m < 64; m <<= 1) v += __shfl_xor(v, m, 64);
        if (lane == 0) red4[wave] = v;
        __syncthreads();
        if (tid == 0) gL[e] = red4[0] + red4[1] + bg2[0];
        __syncthreads();
    }
    float mx = gL[0];
    #pragma unroll
    for (int e = 1; e < 5; e++) mx = fmaxf(mx, gL[e]);
    float wde[5]; float z = 0.0f;
    #pragma unroll
    for (int e = 0; e < 5; e++) { wde[e] = __expf(gL[e] - mx); z += wde[e]; }
    float iz = 1.0f / z;
    #pragma unroll
    for (int e = 0; e < 5; e++) wde[e] *= iz;

    #pragma unroll
    for (int j = 0; j < 3; j++) {
        int h = tid + j * 256;
        float v = 0.0f;
        #pragma unroll
        for (int e = 0; e < 5; e++)
            v += wde[e] * dn[((size_t)(b * 5 + e) * 5 + ii) * HH + h];
        deL[h] = v;
    }
    __syncthreads();

    float part[3] = {0.0f, 0.0f, 0.0f};
    #pragma unroll
    for (int mm = 0; mm < 6; mm++) {
        int h = tid + mm * 256;
        float x = (mm < 3) ? pooled[(size_t)bi * HH + h] : deL[h - HH];
        #pragma unroll
        for (int c = 0; c < 3; c++) part[c] = fmaf(x, wd[(size_t)c * 1536 + h], part[c]);
    }
    #pragma unroll
    for (int c = 0; c < 3; c++) {
        float v = part[c];
        #pragma unroll
        for (int m = 1; m < 64; m <<= 1) v += __shfl_xor(v, m, 64);
        if (lane == 0) red4[wave] = v;
        __syncthreads();
        if (tid == 0) feat[bi * 3 + c] = red4[0] + red4[1] + red4[2] + red4[3] + bd[c];
        __syncthreads();
    }
}

// ---------------------------------------------------------------------------
// K7: final: sel from partials, select softmax over i, class softmax, log
// ---------------------------------------------------------------------------
__global__ __launch_bounds__(64) void k_final(const float* __restrict__ selp,
        const float* __restrict__ denp, const float* __restrict__ bsel,
        const float* __restrict__ feat, float* __restrict__ out) {
    int b = threadIdx.x;
    if (b >= BB) return;
    float sv[5]; float m = -1e30f;
    #pragma unroll
    for (int i = 0; i < 5; i++) {
        float num = 0.0f, den = 0.0f;
        #pragma unroll
        for (int c = 0; c < 5; c++) {
            num += selp[(b * 5 + i) * 5 + c];
            den += denp[(b * 5 + i) * 5 + c];
        }
        sv[i] = bsel[0] + num / (den + 1e-10f);
        m = fmaxf(m, sv[i]);
    }
    float z = 0.0f;
    #pragma unroll
    for (int i = 0; i < 5; i++) { sv[i] = __expf(sv[i] - m); z += sv[i]; }
    #pragma unroll
    for (int i = 0; i < 5; i++) sv[i] /= z;
    float prob[3] = {0.0f, 0.0f, 0.0f};
    #pragma unroll
    for (int i = 0; i < 5; i++) {
        float f0 = feat[(b * 5 + i) * 3 + 0];
        float f1 = feat[(b * 5 + i) * 3 + 1];
        float f2 = feat[(b * 5 + i) * 3 + 2];
        float mm = fmaxf(f0, fmaxf(f1, f2));
        float e0 = __expf(f0 - mm), e1 = __expf(f1 - mm), e2 = __expf(f2 - mm);
        float zz = e0 + e1 + e2;
        prob[0] += sv[i] * e0 / zz;
        prob[1] += sv[i] * e1 / zz;
        prob[2] += sv[i] * e2 / zz;
    }
    #pragma unroll
    for (int c = 0; c < 3; c++) out[b * 3 + c] = __logf(prob[c]);
}

// ---------------------------------------------------------------------------
extern "C" void kernel_launch(void* const* d_in, const int* in_sizes, int n_in,
                              void* d_out, int out_size, void* d_ws, size_t ws_size,
                              hipStream_t stream) {
    const float* hiddens = (const float*)d_in[0];
    const float* pooled  = (const float*)d_in[1];
    const int*   msk     = (const int*)d_in[2];
    const int*   seg     = (const int*)d_in[3];
    const float* Watt    = (const float*)d_in[4];
    const float* batt    = (const float*)d_in[5];
    const float* Wsel    = (const float*)d_in[6];
    const float* bsel    = (const float*)d_in[7];
    const float* Wg1     = (const float*)d_in[8];
    const float* bg1     = (const float*)d_in[9];
    const float* Wg2     = (const float*)d_in[10];
    const float* bg2     = (const float*)d_in[11];
    const float* Wd      = (const float*)d_in[12];
    const float* bd      = (const float*)d_in[13];

    char* ws = (char*)d_ws;
    size_t off = 0;
    auto alloc = [&](size_t bytes) -> void* {
        void* p = ws + off;
        off += (bytes + 255) & ~(size_t)255;
        return p;
    };
    unsigned short* hnbf   = (unsigned short*)alloc((size_t)160 * LL * HH * 2);  // 31.9 MB
    unsigned short* Sg     = (unsigned short*)alloc((size_t)800 * SR * SD * 2);  // 28.3 MB
    float*          score  = (float*)alloc((size_t)800 * LP * 4);
    float*          selp   = (float*)alloc((size_t)160 * 5 * 4);
    float*          denp   = (float*)alloc((size_t)160 * 5 * 4);
    float*          dn     = (float*)alloc((size_t)160 * 5 * HH * 4);            // 2.46 MB
    unsigned short* xg     = (unsigned short*)alloc((size_t)800 * 1536 * 2);
    unsigned short* wg1b   = (unsigned short*)alloc((size_t)128 * 1536 * 2);
    float*          cg     = (float*)alloc((size_t)800 * 128 * 4);
    float*          feat   = (float*)alloc((size_t)800 * 3 * 4);
    (void)ws_size; (void)in_sizes; (void)n_in; (void)out_size;

    k_prologue<<<dim3(6868), dim3(256), 0, stream>>>(hiddens, hnbf, Wg1, wg1b, pooled, xg, cg);
    k_sim_gemm<<<dim3(800), dim3(256), 0, stream>>>(hnbf, Sg);
    k_pool<<<dim3(4000), dim3(256), 0, stream>>>(Sg, msk, seg, Watt, batt, Wsel, score, selp, denp);
    k_attden<<<dim3(480), dim3(256), 0, stream>>>(score, msk, hiddens, dn, xg);
    k_gate_gemm<<<dim3(150), dim3(256), 0, stream>>>(xg, wg1b, cg);
    k_gate_epi<<<dim3(160), dim3(256), 0, stream>>>(cg, bg1, Wg2, bg2, dn, pooled, Wd, bd, feat);
    k_final<<<dim3(1), dim3(64), 0, stream>>>(selp, denp, bsel, feat, (float*)d_out);
}

// Round 9
// 248.766 us; speedup vs baseline: 1.3801x; 1.3801x over previous
//
#include <hip/hip_runtime.h>
#include <cstdint>
#include <cstddef>

#define BB 32
#define EV 5
#define LL 130
#define HH 768
#define KK 21
#define LP 160    // score row stride (padded)
#define SD 136    // compact Sg col count (d < 136)
#define SR 130    // compact Sg row count

typedef __attribute__((ext_vector_type(8))) __bf16 bf16x8;
typedef __attribute__((ext_vector_type(4))) float f32x4;

__device__ __forceinline__ unsigned short f2bf(float f) {
    unsigned int u = __float_as_uint(f);
    u += 0x7FFFu + ((u >> 16) & 1u);   // RNE: keeps ||hn||^2 = 1 +- ~1e-4 (sigma=0.001 kernel!)
    return (unsigned short)(u >> 16);
}
__device__ __forceinline__ float bf2f(unsigned int s) {
    return __uint_as_float(s << 16);
}
// async 16B global -> LDS DMA (no VGPR round-trip; LDS dst = wave-uniform base + lane*16)
__device__ __forceinline__ void gld_lds16(const unsigned short* g, unsigned short* l) {
    __builtin_amdgcn_global_load_lds(
        (const __attribute__((address_space(1))) unsigned int*)g,
        (__attribute__((address_space(3))) unsigned int*)l, 16, 0, 0);
}

// ---------------------------------------------------------------------------
// K1 (merged prologue):
//   blocks [0,5200):     L2-normalize hiddens rows -> bf16 (130 rows per n)
//   blocks [5200,5968):  Wg1 -> bf16
//   blocks [5968,6768):  Xg pooled half
//   blocks [6768,6868):  zero cg (replaces hipMemsetAsync dispatch)
// ---------------------------------------------------------------------------
__global__ __launch_bounds__(256) void k_prologue(const float* __restrict__ hid,
        unsigned short* __restrict__ hnbf, const float* __restrict__ wg1,
        unsigned short* __restrict__ wg1b, const float* __restrict__ pooled,
        unsigned short* __restrict__ xg, float* __restrict__ cg) {
    int bid = blockIdx.x, tid = threadIdx.x;
    if (bid < 5200) {
        int wave = tid >> 6, lane = tid & 63;
        int r = bid * 4 + wave;          // 0 .. 20800
        if (r >= 160 * LL) return;
        const float4* s4 = (const float4*)(hid + (size_t)r * HH);
        float4 v0 = s4[lane], v1 = s4[lane + 64], v2 = s4[lane + 128];
        float ss = v0.x*v0.x + v0.y*v0.y + v0.z*v0.z + v0.w*v0.w
                 + v1.x*v1.x + v1.y*v1.y + v1.z*v1.z + v1.w*v1.w
                 + v2.x*v2.x + v2.y*v2.y + v2.z*v2.z + v2.w*v2.w;
        #pragma unroll
        for (int m = 1; m < 64; m <<= 1) ss += __shfl_xor(ss, m, 64);
        float sc = 1.0f / fmaxf(sqrtf(ss), 1e-12f);
        ushort4 o0, o1, o2;
        o0.x = f2bf(v0.x*sc); o0.y = f2bf(v0.y*sc); o0.z = f2bf(v0.z*sc); o0.w = f2bf(v0.w*sc);
        o1.x = f2bf(v1.x*sc); o1.y = f2bf(v1.y*sc); o1.z = f2bf(v1.z*sc); o1.w = f2bf(v1.w*sc);
        o2.x = f2bf(v2.x*sc); o2.y = f2bf(v2.y*sc); o2.z = f2bf(v2.z*sc); o2.w = f2bf(v2.w*sc);
        ushort4* d4 = (ushort4*)(hnbf + (size_t)r * HH);
        d4[lane] = o0; d4[lane + 64] = o1; d4[lane + 128] = o2;
    } else if (bid < 5968) {
        int idx = (bid - 5200) * 256 + tid;      // < 196608 exactly
        wg1b[idx] = f2bf(wg1[idx]);
    } else if (bid < 6768) {
        int row = bid - 5968;                    // 0..799
        int bi = row / 5;
        const float* src = pooled + (size_t)bi * HH;
        unsigned short* dst = xg + (size_t)row * 1536;
        #pragma unroll
        for (int j = 0; j < 3; j++) { int h = tid + j * 256; dst[h] = f2bf(src[h]); }
    } else {
        int slot = (bid - 6768) * 256 + tid;     // 100*256 slots x 4 floats = 102400
        float4 z = (float4){0.f, 0.f, 0.f, 0.f};
        *(float4*)&cg[(size_t)slot * 4] = z;
    }
}

// ---------------------------------------------------------------------------
// K2: batched similarity GEMM. Async-DMA double-buffer, single barrier/step.
// Per k-step: issue global_load_lds DMAs for k+1 into buf[nxt] (ZERO VGPRs —
// no spill, unlike the rd-8 register prefetch), ds_read+MFMA from buf[cur],
// then ONE barrier whose vmcnt(0) drain overlaps the MFMA phase just done.
// Bank-conflict-free XOR (proven 0 in rd 8): LDS seg s&3 of row r holds
// global seg (s&3)^((r>>1)&3); read seg = quad^((row>>1)&3) -> each 4-bank
// span hit by exactly 2 lanes (free). DMA writes are lane-contiguous (free).
// 800 blocks; xcd = bid&7 owns b in [4*xcd, 4*xcd+4) for L2 locality.
// ---------------------------------------------------------------------------
__global__ __launch_bounds__(256) void k_sim_gemm(const unsigned short* __restrict__ hnbf,
                                                  unsigned short* __restrict__ Sg) {
    int w = blockIdx.x;
    int xcd = w & 7, slot = w >> 3;            // 800 = 8*100
    int b = xcd * 4 + (slot / 25);
    int ei = slot % 25;
    int e = ei / 5, i = ei % 5;
    int pair = b * 25 + ei;
    const unsigned short* A = hnbf + (size_t)(b * 5 + e) * LL * HH;
    const unsigned short* B = hnbf + (size_t)(b * 5 + i) * LL * HH;
    __shared__ unsigned short As[2][160 * 32];
    __shared__ unsigned short Bs[2][160 * 32];
    int tid = threadIdx.x, lane = tid & 63, wave = tid >> 6;
    int quad = lane >> 4, l16 = lane & 15;
    int wm = (wave & 1) * 5, wn = (wave >> 1) * 5;

    // staging: slot s in [0,640): row r=s>>2; LDS seg s&3 (at s*8 shorts)
    // holds global seg (s&3)^((r>>1)&3) of row r.
    int goff[3];
    #pragma unroll
    for (int it = 0; it < 3; it++) {
        int s = tid + it * 256;
        int r = s >> 2;
        int rs = (r < LL) ? r : 0;              // clamp: finite junk, masked later
        goff[it] = rs * HH + (((s & 3) ^ ((r >> 1) & 3)) * 8);
    }
    // per-wave LDS read offsets (shorts), constant over the k-loop
    int rdA[5], rdB[5];
    #pragma unroll
    for (int t = 0; t < 5; t++) {
        int ra = (wm + t) * 16 + l16;
        int rb = (wn + t) * 16 + l16;
        rdA[t] = ra * 32 + (quad ^ ((ra >> 1) & 3)) * 8;
        rdB[t] = rb * 32 + (quad ^ ((rb >> 1) & 3)) * 8;
    }

    auto STAGE = [&](int buf, int k0) {
        #pragma unroll
        for (int it = 0; it < 3; it++) {
            int s = tid + it * 256;
            if (s < 640) {
                gld_lds16(A + goff[it] + k0, &As[buf][s * 8]);
                gld_lds16(B + goff[it] + k0, &Bs[buf][s * 8]);
            }
        }
    };

    f32x4 acc[5][5];
    #pragma unroll
    for (int mt = 0; mt < 5; mt++)
        #pragma unroll
        for (int nt = 0; nt < 5; nt++) acc[mt][nt] = (f32x4){0.f, 0.f, 0.f, 0.f};

    STAGE(0, 0);
    __syncthreads();
    for (int ks = 0; ks < 24; ks++) {
        int cur = ks & 1;
        if (ks < 23) STAGE(cur ^ 1, (ks + 1) * 32);   // async DMA, overlaps MFMA below
        bf16x8 af[5], bfr[5];
        #pragma unroll
        for (int t = 0; t < 5; t++) {
            af[t]  = *(const bf16x8*)&As[cur][rdA[t]];
            bfr[t] = *(const bf16x8*)&Bs[cur][rdB[t]];
        }
        #pragma unroll
        for (int mt = 0; mt < 5; mt++)
            #pragma unroll
            for (int nt = 0; nt < 5; nt++)
                acc[mt][nt] = __builtin_amdgcn_mfma_f32_16x16x32_bf16(af[mt], bfr[nt], acc[mt][nt], 0, 0, 0);
        __syncthreads();   // vmcnt(0) drain here overlapped with the MFMAs above
    }

    size_t base = (size_t)pair * SR * SD;
    #pragma unroll
    for (int mt = 0; mt < 5; mt++)
        #pragma unroll
        for (int nt = 0; nt < 5; nt++) {
            int R0 = (wm + mt) * 16 + quad * 4;
            int C = (wn + nt) * 16 + l16;
            if (C < SD) {
                #pragma unroll
                for (int reg = 0; reg < 4; reg++) {
                    int R = R0 + reg;
                    if (R < SR) Sg[base + (size_t)R * SD + C] = f2bf(acc[mt][nt][reg]);
                }
            }
        }
}

// ---------------------------------------------------------------------------
// K3: kernel-pool. grid 4000, XCD-swizzled to match k_sim_gemm's b placement.
// 26 rows per block, 8 lanes per row streaming 16B uint4 from compact Sg.
// Gaussian-grid trick: exp(-50(s-mu_k)^2) = C_k * u * r^(k-1),
//   u=exp(-50 s^2+95 s), r=exp(-10 s), C_k=exp(-50 mu_k^2); k=0 direct.
// ---------------------------------------------------------------------------
template <bool DIAG>
__device__ __forceinline__ void pool_body(
    int pair, int row, int lane8, bool live, int ne, int c,
    const unsigned short* __restrict__ Sg,
    const float* __restrict__ batt,
    float* __restrict__ score, float* __restrict__ selp, float* __restrict__ denp,
    const float* wdA, const float* wdE, const float* wqC,
    const float* WaL, const float* WsL, const float* CkL,
    float* redsel, float* redden) {

    const float LOG2E = 1.4426950408889634f;
    const float CA = -50.0f * LOG2E;
    const float CB = 95.0f * LOG2E;
    const float CR = -10.0f * LOG2E;
    const float C0 = -500000.0f * LOG2E;
    int tid = threadIdx.x;

    float a0[KK], a2[KK];
    #pragma unroll
    for (int k = 0; k < KK; k++) { a0[k] = 0.0f; a2[k] = 0.0f; }

    auto proc = [&](float s, int d) {
        float w = wdA[d];
        float w2 = DIAG ? wdE[d] : 0.0f;
        float pe = exp2f(fmaf(CB, s, CA * s * s));
        float rr = exp2f(CR * s);
        float sm1 = s - 1.0f;
        float e0 = exp2f(C0 * (sm1 * sm1));
        a0[0] = fmaf(w, e0, a0[0]);
        if (DIAG) a2[0] = fmaf(w2, e0, a2[0]);
        float p = pe;
        #pragma unroll
        for (int k = 1; k < KK; k++) {
            a0[k] = fmaf(w, p, a0[k]);
            if (DIAG) a2[k] = fmaf(w2, p, a2[k]);
            p *= rr;
        }
    };

    if (live) {
        const unsigned short* Srow = Sg + (size_t)pair * SR * SD + (size_t)row * SD;
        #pragma unroll
        for (int j = 0; j < 2; j++) {
            uint4 v = *(const uint4*)(Srow + lane8 * 8 + j * 64);
            int d0 = lane8 * 8 + j * 64;
            proc(bf2f(v.x & 0xFFFFu), d0 + 0); proc(bf2f(v.x >> 16), d0 + 1);
            proc(bf2f(v.y & 0xFFFFu), d0 + 2); proc(bf2f(v.y >> 16), d0 + 3);
            proc(bf2f(v.z & 0xFFFFu), d0 + 4); proc(bf2f(v.z >> 16), d0 + 5);
            proc(bf2f(v.w & 0xFFFFu), d0 + 6); proc(bf2f(v.w >> 16), d0 + 7);
        }
        proc(bf2f((unsigned int)Srow[128 + lane8]), 128 + lane8);  // d in [128,136)
    }
    #pragma unroll
    for (int k = 0; k < KK; k++) {
        a0[k] += __shfl_xor(a0[k], 1, 64);
        a0[k] += __shfl_xor(a0[k], 2, 64);
        a0[k] += __shfl_xor(a0[k], 4, 64);
        if (DIAG) {
            a2[k] += __shfl_xor(a2[k], 1, 64);
            a2[k] += __shfl_xor(a2[k], 2, 64);
            a2[k] += __shfl_xor(a2[k], 4, 64);
        }
    }
    float selv = 0.0f, denv = 0.0f;
    if (live && lane8 == 0) {
        float sc = batt[0];
        #pragma unroll
        for (int k = 0; k < KK; k++)
            sc += WaL[k] * __logf(fmaxf(CkL[k] * a0[k], 1e-10f));
        score[(size_t)pair * LP + row] = sc;
        if (DIAG) {
            float cq = 0.0f;
            #pragma unroll
            for (int k = 0; k < KK; k++)
                cq += WsL[k] * __logf(fmaxf(CkL[k] * a2[k], 1e-10f));
            selv = wqC[row] * cq;
            denv = wqC[row];
        }
    }
    if (DIAG) {
        #pragma unroll
        for (int m = 8; m < 64; m <<= 1) {
            selv += __shfl_xor(selv, m, 64);
            denv += __shfl_xor(denv, m, 64);
        }
        int wave = tid >> 6, lane = tid & 63;
        if (lane == 0) { redsel[wave] = selv; redden[wave] = denv; }
        __syncthreads();
        if (tid == 0) {
            selp[ne * 5 + c] = redsel[0] + redsel[1] + redsel[2] + redsel[3];
            denp[ne * 5 + c] = redden[0] + redden[1] + redden[2] + redden[3];
        }
    }
}

__global__ __launch_bounds__(256) void k_pool(const unsigned short* __restrict__ Sg,
        const int* __restrict__ msk, const int* __restrict__ seg,
        const float* __restrict__ Watt, const float* __restrict__ batt,
        const float* __restrict__ Wsel,
        float* __restrict__ score, float* __restrict__ selp, float* __restrict__ denp) {
    __shared__ float wdA[SD], wdE[SD], wqC[SD];
    __shared__ float WaL[KK], WsL[KK], CkL[KK];
    __shared__ float redsel[4], redden[4];
    int w = blockIdx.x;                       // 4000 = 8 * 500
    int xcd = w & 7, slot = w >> 3;
    int b = xcd * 4 + (slot / 125);
    int rem = slot % 125;
    int ei = rem / 5, c = rem % 5;
    int e = ei / 5, i = ei % 5;
    int pair = b * 25 + ei;
    int ne = b * 5 + e, ni = b * 5 + i;
    int tid = threadIdx.x;

    if (tid < SD) {
        int d = tid;
        wdA[d] = (d >= 1 && d < LL) ? (float)msk[ni * LL + d] : 0.0f;
        float mtE = (d >= 1 && d < LL) ? (float)msk[ne * LL + d] : 0.0f;
        float sgE = (d < LL) ? (float)seg[ne * LL + d] : 0.0f;
        wdE[d] = sgE * mtE;
        wqC[d] = (1.0f - sgE) * mtE;
    }
    if (tid < KK) {
        const float LOG2E = 1.4426950408889634f;
        WaL[tid] = Watt[tid];
        WsL[tid] = Wsel[tid];
        float mu = 0.95f - 0.1f * (tid - 1);
        CkL[tid] = (tid == 0) ? 1.0f : exp2f(-50.0f * LOG2E * mu * mu);
    }
    __syncthreads();

    int row = c * 26 + (tid >> 3);
    int lane8 = tid & 7;
    bool live = (tid < 208);               // 26 rows * 8 lanes

    if (e == i)
        pool_body<true>(pair, row, lane8, live, ne, c, Sg, batt, score, selp, denp,
                        wdA, wdE, wqC, WaL, WsL, CkL, redsel, redden);
    else
        pool_body<false>(pair, row, lane8, live, ne, c, Sg, batt, score, selp, denp,
                         wdA, wdE, wqC, WaL, WsL, CkL, redsel, redden);
}

// ---------------------------------------------------------------------------
// K4 (fused att+den): grid 480 (be, j). Phase 1: waves compute the 5 masked
// softmaxes into LDS (wave w handles i = w, w+4). Phase 2: denoise chunk j.
// ---------------------------------------------------------------------------
__global__ __launch_bounds__(256) void k_attden(const float* __restrict__ score,
        const int* __restrict__ msk, const float* __restrict__ hid,
        float* __restrict__ dn, unsigned short* __restrict__ xg) {
    int bid = blockIdx.x;
    int be = bid / 3, j = bid % 3;
    int b = be / 5, e = be % 5;
    int tid = threadIdx.x, lane = tid & 63, wave = tid >> 6;
    __shared__ float attl[5 * 132];

    for (int i = wave; i < 5; i += 4) {
        const float* srow = score + ((size_t)(b * 5 + i) * 5 + e) * LP;
        float v0, v1, v2 = -1e30f;
        {
            int q = lane;
            bool mt = (q >= 1 && msk[be * LL + q] != 0);
            v0 = mt ? srow[q] : -1e4f;
        }
        {
            int q = lane + 64;
            bool mt = (msk[be * LL + q] != 0);
            v1 = mt ? srow[q] : -1e4f;
        }
        if (lane < 2) {
            int q = lane + 128;
            bool mt = (msk[be * LL + q] != 0);
            v2 = mt ? srow[q] : -1e4f;
        }
        float mx = fmaxf(v0, fmaxf(v1, v2));
        #pragma unroll
        for (int m = 1; m < 64; m <<= 1) mx = fmaxf(mx, __shfl_xor(mx, m, 64));
        float e0 = __expf(v0 - mx), e1 = __expf(v1 - mx);
        float e2 = (lane < 2) ? __expf(v2 - mx) : 0.0f;
        float Z = e0 + e1 + e2;
        #pragma unroll
        for (int m = 1; m < 64; m <<= 1) Z += __shfl_xor(Z, m, 64);
        float iz = 1.0f / Z;
        attl[i * 132 + lane] = e0 * iz;
        attl[i * 132 + lane + 64] = e1 * iz;
        if (lane < 2) attl[i * 132 + lane + 128] = e2 * iz;
    }
    __syncthreads();

    int h = j * 256 + tid;
    float accA[5] = {0.f, 0.f, 0.f, 0.f, 0.f};
    float accB[5] = {0.f, 0.f, 0.f, 0.f, 0.f};
    const float* hb = hid + (size_t)be * LL * HH + h;
    int q = 0;
    #pragma unroll 2
    for (; q + 4 <= LL; q += 4) {
        float h0 = hb[(size_t)(q + 0) * HH];
        float h1 = hb[(size_t)(q + 1) * HH];
        float h2 = hb[(size_t)(q + 2) * HH];
        float h3 = hb[(size_t)(q + 3) * HH];
        #pragma unroll
        for (int i = 0; i < 5; i++) {
            accA[i] = fmaf(attl[i * 132 + q], h0, accA[i]);
            accB[i] = fmaf(attl[i * 132 + q + 1], h1, accB[i]);
            accA[i] = fmaf(attl[i * 132 + q + 2], h2, accA[i]);
            accB[i] = fmaf(attl[i * 132 + q + 3], h3, accB[i]);
        }
    }
    for (; q < LL; q++) {
        float hv = hb[(size_t)q * HH];
        #pragma unroll
        for (int i = 0; i < 5; i++) accA[i] = fmaf(attl[i * 132 + q], hv, accA[i]);
    }
    #pragma unroll
    for (int i = 0; i < 5; i++) {
        float v = accA[i] + accB[i];
        dn[((size_t)be * 5 + i) * HH + h] = v;
        xg[((size_t)(b * 5 + i) * 5 + e) * 1536 + HH + h] = f2bf(v);
    }
}

// ---------------------------------------------------------------------------
// K5: gating GEMM Cg[800][128] += Xg[800][1536] @ Wg1^T, 3-way K-split,
// f32 atomics into prologue-zeroed cg. grid 150: bid = rb*3 + ks.
// ---------------------------------------------------------------------------
__global__ __launch_bounds__(256) void k_gate_gemm(const unsigned short* __restrict__ xg,
        const unsigned short* __restrict__ wg1b, float* __restrict__ cg) {
    int bid = blockIdx.x;
    int rb = bid / 3, ks = bid % 3;
    int m0 = rb * 16;
    __shared__ unsigned short As[16 * 32];
    __shared__ unsigned short Bs[128 * 32];
    int tid = threadIdx.x, lane = tid & 63, wave = tid >> 6;
    int quad = lane >> 4, l16 = lane & 15;
    f32x4 acc[2];
    acc[0] = (f32x4){0.f, 0.f, 0.f, 0.f};
    acc[1] = (f32x4){0.f, 0.f, 0.f, 0.f};

    for (int t = 0; t < 16; t++) {
        int k0 = ks * 512 + t * 32;
        if (tid < 64) {
            int row = tid >> 2, sg = tid & 3;
            *(uint4*)&As[tid * 8] = *(const uint4*)(xg + (size_t)(m0 + row) * 1536 + k0 + sg * 8);
        }
        #pragma unroll
        for (int it = 0; it < 2; it++) {
            int s = tid + it * 256;
            int row = s >> 2, sg = s & 3;
            *(uint4*)&Bs[s * 8] = *(const uint4*)(wg1b + (size_t)row * 1536 + k0 + sg * 8);
        }
        __syncthreads();
        bf16x8 af = *(const bf16x8*)&As[l16 * 32 + quad * 8];
        #pragma unroll
        for (int nt = 0; nt < 2; nt++) {
            int ct = wave * 2 + nt;
            bf16x8 bfr = *(const bf16x8*)&Bs[(ct * 16 + l16) * 32 + quad * 8];
            acc[nt] = __builtin_amdgcn_mfma_f32_16x16x32_bf16(af, bfr, acc[nt], 0, 0, 0);
        }
        __syncthreads();
    }
    #pragma unroll
    for (int nt = 0; nt < 2; nt++) {
        int C = (wave * 2 + nt) * 16 + l16;
        #pragma unroll
        for (int reg = 0; reg < 4; reg++) {
            int R = m0 + quad * 4 + reg;
            atomicAdd(&cg[(size_t)R * 128 + C], acc[nt][reg]);
        }
    }
}

// ---------------------------------------------------------------------------
// K6: per (b,i): g[e] = Wg2.relu(cg+bg1)+bg2; softmax_e; de; feat = Wd.concat
// ---------------------------------------------------------------------------
__global__ __launch_bounds__(256) void k_gate_epi(const float* __restrict__ cg,
        const float* __restrict__ bg1, const float* __restrict__ wg2,
        const float* __restrict__ bg2, const float* __restrict__ dn,
        const float* __restrict__ pooled, const float* __restrict__ wd,
        const float* __restrict__ bd, float* __restrict__ feat) {
    int bi = blockIdx.x;                 // b*5+i
    int b = bi / 5, ii = bi % 5;
    __shared__ float red4[4];
    __shared__ float gL[5];
    __shared__ float deL[HH];
    int tid = threadIdx.x, lane = tid & 63, wave = tid >> 6;

    for (int e = 0; e < 5; e++) {
        float v = 0.0f;
        if (tid < 128) {
            float ccv = cg[(size_t)(bi * 5 + e) * 128 + tid] + bg1[tid];
            v = wg2[tid] * fmaxf(ccv, 0.0f);
        }
        #pragma unroll
        for (int m = 1; m < 64; m <<= 1) v += __shfl_xor(v, m, 64);
        if (lane == 0) red4[wave] = v;
        __syncthreads();
        if (tid == 0) gL[e] = red4[0] + red4[1] + bg2[0];
        __syncthreads();
    }
    float mx = gL[0];
    #pragma unroll
    for (int e = 1; e < 5; e++) mx = fmaxf(mx, gL[e]);
    float wde[5]; float z = 0.0f;
    #pragma unroll
    for (int e = 0; e < 5; e++) { wde[e] = __expf(gL[e] - mx); z += wde[e]; }
    float iz = 1.0f / z;
    #pragma unroll
    for (int e = 0; e < 5; e++) wde[e] *= iz;

    #pragma unroll
    for (int j = 0; j < 3; j++) {
        int h = tid + j * 256;
        float v = 0.0f;
        #pragma unroll
        for (int e = 0; e < 5; e++)
            v += wde[e] * dn[((size_t)(b * 5 + e) * 5 + ii) * HH + h];
        deL[h] = v;
    }
    __syncthreads();

    float part[3] = {0.0f, 0.0f, 0.0f};
    #pragma unroll
    for (int mm = 0; mm < 6; mm++) {
        int h = tid + mm * 256;
        float x = (mm < 3) ? pooled[(size_t)bi * HH + h] : deL[h - HH];
        #pragma unroll
        for (int c = 0; c < 3; c++) part[c] = fmaf(x, wd[(size_t)c * 1536 + h], part[c]);
    }
    #pragma unroll
    for (int c = 0; c < 3; c++) {
        float v = part[c];
        #pragma unroll
        for (int m = 1; m < 64; m <<= 1) v += __shfl_xor(v, m, 64);
        if (lane == 0) red4[wave] = v;
        __syncthreads();
        if (tid == 0) feat[bi * 3 + c] = red4[0] + red4[1] + red4[2] + red4[3] + bd[c];
        __syncthreads();
    }
}

// ---------------------------------------------------------------------------
// K7: final: sel from partials, select softmax over i, class softmax, log
// ---------------------------------------------------------------------------
__global__ __launch_bounds__(64) void k_final(const float* __restrict__ selp,
        const float* __restrict__ denp, const float* __restrict__ bsel,
        const float* __restrict__ feat, float* __restrict__ out) {
    int b = threadIdx.x;
    if (b >= BB) return;
    float sv[5]; float m = -1e30f;
    #pragma unroll
    for (int i = 0; i < 5; i++) {
        float num = 0.0f, den = 0.0f;
        #pragma unroll
        for (int c = 0; c < 5; c++) {
            num += selp[(b * 5 + i) * 5 + c];
            den += denp[(b * 5 + i) * 5 + c];
        }
        sv[i] = bsel[0] + num / (den + 1e-10f);
        m = fmaxf(m, sv[i]);
    }
    float z = 0.0f;
    #pragma unroll
    for (int i = 0; i < 5; i++) { sv[i] = __expf(sv[i] - m); z += sv[i]; }
    #pragma unroll
    for (int i = 0; i < 5; i++) sv[i] /= z;
    float prob[3] = {0.0f, 0.0f, 0.0f};
    #pragma unroll
    for (int i = 0; i < 5; i++) {
        float f0 = feat[(b * 5 + i) * 3 + 0];
        float f1 = feat[(b * 5 + i) * 3 + 1];
        float f2 = feat[(b * 5 + i) * 3 + 2];
        float mm = fmaxf(f0, fmaxf(f1, f2));
        float e0 = __expf(f0 - mm), e1 = __expf(f1 - mm), e2 = __expf(f2 - mm);
        float zz = e0 + e1 + e2;
        prob[0] += sv[i] * e0 / zz;
        prob[1] += sv[i] * e1 / zz;
        prob[2] += sv[i] * e2 / zz;
    }
    #pragma unroll
    for (int c = 0; c < 3; c++) out[b * 3 + c] = __logf(prob[c]);
}

// ---------------------------------------------------------------------------
extern "C" void kernel_launch(void* const* d_in, const int* in_sizes, int n_in,
                              void* d_out, int out_size, void* d_ws, size_t ws_size,
                              hipStream_t stream) {
    const float* hiddens = (const float*)d_in[0];
    const float* pooled  = (const float*)d_in[1];
    const int*   msk     = (const int*)d_in[2];
    const int*   seg     = (const int*)d_in[3];
    const float* Watt    = (const float*)d_in[4];
    const float* batt    = (const float*)d_in[5];
    const float* Wsel    = (const float*)d_in[6];
    const float* bsel    = (const float*)d_in[7];
    const float* Wg1     = (const float*)d_in[8];
    const float* bg1     = (const float*)d_in[9];
    const float* Wg2     = (const float*)d_in[10];
    const float* bg2     = (const float*)d_in[11];
    const float* Wd      = (const float*)d_in[12];
    const float* bd      = (const float*)d_in[13];

    char* ws = (char*)d_ws;
    size_t off = 0;
    auto alloc = [&](size_t bytes) -> void* {
        void* p = ws + off;
        off += (bytes + 255) & ~(size_t)255;
        return p;
    };
    unsigned short* hnbf   = (unsigned short*)alloc((size_t)160 * LL * HH * 2);  // 31.9 MB
    unsigned short* Sg     = (unsigned short*)alloc((size_t)800 * SR * SD * 2);  // 28.3 MB
    float*          score  = (float*)alloc((size_t)800 * LP * 4);
    float*          selp   = (float*)alloc((size_t)160 * 5 * 4);
    float*          denp   = (float*)alloc((size_t)160 * 5 * 4);
    float*          dn     = (float*)alloc((size_t)160 * 5 * HH * 4);            // 2.46 MB
    unsigned short* xg     = (unsigned short*)alloc((size_t)800 * 1536 * 2);
    unsigned short* wg1b   = (unsigned short*)alloc((size_t)128 * 1536 * 2);
    float*          cg     = (float*)alloc((size_t)800 * 128 * 4);
    float*          feat   = (float*)alloc((size_t)800 * 3 * 4);
    (void)ws_size; (void)in_sizes; (void)n_in; (void)out_size;

    k_prologue<<<dim3(6868), dim3(256), 0, stream>>>(hiddens, hnbf, Wg1, wg1b, pooled, xg, cg);
    k_sim_gemm<<<dim3(800), dim3(256), 0, stream>>>(hnbf, Sg);
    k_pool<<<dim3(4000), dim3(256), 0, stream>>>(Sg, msk, seg, Watt, batt, Wsel, score, selp, denp);
    k_attden<<<dim3(480), dim3(256), 0, stream>>>(score, msk, hiddens, dn, xg);
    k_gate_gemm<<<dim3(150), dim3(256), 0, stream>>>(xg, wg1b, cg);
    k_gate_epi<<<dim3(160), dim3(256), 0, stream>>>(cg, bg1, Wg2, bg2, dn, pooled, Wd, bd, feat);
    k_final<<<dim3(1), dim3(64), 0, stream>>>(selp, denp, bsel, feat, (float*)d_out);
}

// Round 10
// 231.259 us; speedup vs baseline: 1.4846x; 1.0757x over previous
//
#include <hip/hip_runtime.h>
#include <cstdint>
#include <cstddef>

#define BB 32
#define EV 5
#define LL 130
#define HH 768
#define KK 21
#define LP 160    // score row stride (padded)
#define SD 136    // compact Sg col count (d < 136)
#define SR 130    // compact Sg row count

typedef __attribute__((ext_vector_type(8))) __bf16 bf16x8;
typedef __attribute__((ext_vector_type(4))) float f32x4;

__device__ __forceinline__ unsigned short f2bf(float f) {
    unsigned int u = __float_as_uint(f);
    u += 0x7FFFu + ((u >> 16) & 1u);   // RNE: keeps ||hn||^2 = 1 +- ~1e-4 (sigma=0.001 kernel!)
    return (unsigned short)(u >> 16);
}
__device__ __forceinline__ float bf2f(unsigned int s) {
    return __uint_as_float(s << 16);
}
// async 16B global -> LDS DMA (no VGPR round-trip; LDS dst = wave-uniform base + lane*16)
__device__ __forceinline__ void gld_lds16(const unsigned short* g, unsigned short* l) {
    __builtin_amdgcn_global_load_lds(
        (const __attribute__((address_space(1))) unsigned int*)g,
        (__attribute__((address_space(3))) unsigned int*)l, 16, 0, 0);
}

// ---------------------------------------------------------------------------
// K1 (merged prologue):
//   blocks [0,5200):     L2-normalize hiddens rows -> bf16 (130 rows per n)
//   blocks [5200,5968):  Wg1 -> bf16
//   blocks [5968,6768):  Xg pooled half
//   blocks [6768,6868):  zero cg (replaces hipMemsetAsync dispatch)
// ---------------------------------------------------------------------------
__global__ __launch_bounds__(256) void k_prologue(const float* __restrict__ hid,
        unsigned short* __restrict__ hnbf, const float* __restrict__ wg1,
        unsigned short* __restrict__ wg1b, const float* __restrict__ pooled,
        unsigned short* __restrict__ xg, float* __restrict__ cg) {
    int bid = blockIdx.x, tid = threadIdx.x;
    if (bid < 5200) {
        int wave = tid >> 6, lane = tid & 63;
        int r = bid * 4 + wave;          // 0 .. 20800
        if (r >= 160 * LL) return;
        const float4* s4 = (const float4*)(hid + (size_t)r * HH);
        float4 v0 = s4[lane], v1 = s4[lane + 64], v2 = s4[lane + 128];
        float ss = v0.x*v0.x + v0.y*v0.y + v0.z*v0.z + v0.w*v0.w
                 + v1.x*v1.x + v1.y*v1.y + v1.z*v1.z + v1.w*v1.w
                 + v2.x*v2.x + v2.y*v2.y + v2.z*v2.z + v2.w*v2.w;
        #pragma unroll
        for (int m = 1; m < 64; m <<= 1) ss += __shfl_xor(ss, m, 64);
        float sc = 1.0f / fmaxf(sqrtf(ss), 1e-12f);
        ushort4 o0, o1, o2;
        o0.x = f2bf(v0.x*sc); o0.y = f2bf(v0.y*sc); o0.z = f2bf(v0.z*sc); o0.w = f2bf(v0.w*sc);
        o1.x = f2bf(v1.x*sc); o1.y = f2bf(v1.y*sc); o1.z = f2bf(v1.z*sc); o1.w = f2bf(v1.w*sc);
        o2.x = f2bf(v2.x*sc); o2.y = f2bf(v2.y*sc); o2.z = f2bf(v2.z*sc); o2.w = f2bf(v2.w*sc);
        ushort4* d4 = (ushort4*)(hnbf + (size_t)r * HH);
        d4[lane] = o0; d4[lane + 64] = o1; d4[lane + 128] = o2;
    } else if (bid < 5968) {
        int idx = (bid - 5200) * 256 + tid;      // < 196608 exactly
        wg1b[idx] = f2bf(wg1[idx]);
    } else if (bid < 6768) {
        int row = bid - 5968;                    // 0..799
        int bi = row / 5;
        const float* src = pooled + (size_t)bi * HH;
        unsigned short* dst = xg + (size_t)row * 1536;
        #pragma unroll
        for (int j = 0; j < 3; j++) { int h = tid + j * 256; dst[h] = f2bf(src[h]); }
    } else {
        int slot = (bid - 6768) * 256 + tid;     // 100*256 slots x 4 floats = 102400
        float4 z = (float4){0.f, 0.f, 0.f, 0.f};
        *(float4*)&cg[(size_t)slot * 4] = z;
    }
}

// ---------------------------------------------------------------------------
// K2: batched similarity GEMM. Async-DMA double-buffer, single barrier/step.
// (unchanged from round 9 — measured <58us, 0 conflicts, no spill)
// ---------------------------------------------------------------------------
__global__ __launch_bounds__(256) void k_sim_gemm(const unsigned short* __restrict__ hnbf,
                                                  unsigned short* __restrict__ Sg) {
    int w = blockIdx.x;
    int xcd = w & 7, slot = w >> 3;            // 800 = 8*100
    int b = xcd * 4 + (slot / 25);
    int ei = slot % 25;
    int e = ei / 5, i = ei % 5;
    int pair = b * 25 + ei;
    const unsigned short* A = hnbf + (size_t)(b * 5 + e) * LL * HH;
    const unsigned short* B = hnbf + (size_t)(b * 5 + i) * LL * HH;
    __shared__ unsigned short As[2][160 * 32];
    __shared__ unsigned short Bs[2][160 * 32];
    int tid = threadIdx.x, lane = tid & 63, wave = tid >> 6;
    int quad = lane >> 4, l16 = lane & 15;
    int wm = (wave & 1) * 5, wn = (wave >> 1) * 5;

    int goff[3];
    #pragma unroll
    for (int it = 0; it < 3; it++) {
        int s = tid + it * 256;
        int r = s >> 2;
        int rs = (r < LL) ? r : 0;              // clamp: finite junk, masked later
        goff[it] = rs * HH + (((s & 3) ^ ((r >> 1) & 3)) * 8);
    }
    int rdA[5], rdB[5];
    #pragma unroll
    for (int t = 0; t < 5; t++) {
        int ra = (wm + t) * 16 + l16;
        int rb = (wn + t) * 16 + l16;
        rdA[t] = ra * 32 + (quad ^ ((ra >> 1) & 3)) * 8;
        rdB[t] = rb * 32 + (quad ^ ((rb >> 1) & 3)) * 8;
    }

    auto STAGE = [&](int buf, int k0) {
        #pragma unroll
        for (int it = 0; it < 3; it++) {
            int s = tid + it * 256;
            if (s < 640) {
                gld_lds16(A + goff[it] + k0, &As[buf][s * 8]);
                gld_lds16(B + goff[it] + k0, &Bs[buf][s * 8]);
            }
        }
    };

    f32x4 acc[5][5];
    #pragma unroll
    for (int mt = 0; mt < 5; mt++)
        #pragma unroll
        for (int nt = 0; nt < 5; nt++) acc[mt][nt] = (f32x4){0.f, 0.f, 0.f, 0.f};

    STAGE(0, 0);
    __syncthreads();
    for (int ks = 0; ks < 24; ks++) {
        int cur = ks & 1;
        if (ks < 23) STAGE(cur ^ 1, (ks + 1) * 32);   // async DMA, overlaps MFMA below
        bf16x8 af[5], bfr[5];
        #pragma unroll
        for (int t = 0; t < 5; t++) {
            af[t]  = *(const bf16x8*)&As[cur][rdA[t]];
            bfr[t] = *(const bf16x8*)&Bs[cur][rdB[t]];
        }
        #pragma unroll
        for (int mt = 0; mt < 5; mt++)
            #pragma unroll
            for (int nt = 0; nt < 5; nt++)
                acc[mt][nt] = __builtin_amdgcn_mfma_f32_16x16x32_bf16(af[mt], bfr[nt], acc[mt][nt], 0, 0, 0);
        __syncthreads();   // vmcnt(0) drain here overlapped with the MFMAs above
    }

    size_t base = (size_t)pair * SR * SD;
    #pragma unroll
    for (int mt = 0; mt < 5; mt++)
        #pragma unroll
        for (int nt = 0; nt < 5; nt++) {
            int R0 = (wm + mt) * 16 + quad * 4;
            int C = (wn + nt) * 16 + l16;
            if (C < SD) {
                #pragma unroll
                for (int reg = 0; reg < 4; reg++) {
                    int R = R0 + reg;
                    if (R < SR) Sg[base + (size_t)R * SD + C] = f2bf(acc[mt][nt][reg]);
                }
            }
        }
}

// ---------------------------------------------------------------------------
// K3: kernel-pool. grid 4000, XCD-swizzled. 26 rows/block, 8 lanes/row.
// Round-10 changes: raw v_exp/v_log builtins (log2 + ln2 folded into W in
// LDS), vectorized mask loads (4x ds_read_b128 + 1 b32 instead of 17 b32),
// log epilogue distributed over the 8 lanes (k = lane8 + {0,8,16}).
// Gaussian-grid trick: exp(-50(s-mu_k)^2) = C_k * u * r^(k-1),
//   u=exp2(CA s^2+CB s), r=exp2(CR s), C_k=exp2(CA mu_k^2); k=0 direct.
// ---------------------------------------------------------------------------
template <bool DIAG>
__device__ __forceinline__ void pool_body(
    int pair, int row, int lane8, bool live, int ne, int c,
    const unsigned short* __restrict__ Sg,
    const float* __restrict__ batt,
    float* __restrict__ score, float* __restrict__ selp, float* __restrict__ denp,
    const float* wdA, const float* wdE, const float* wqC,
    const float* WaL, const float* WsL, const float* CkL,
    float* redsel, float* redden) {

    const float LOG2E = 1.4426950408889634f;
    const float CA = -50.0f * LOG2E;
    const float CB = 95.0f * LOG2E;
    const float CR = -10.0f * LOG2E;
    const float C0 = -500000.0f * LOG2E;
    int tid = threadIdx.x;

    float a0[KK], a2[KK];
    #pragma unroll
    for (int k = 0; k < KK; k++) { a0[k] = 0.0f; a2[k] = 0.0f; }

    // hoisted, vectorized mask loads: lane's 17 d's are [l8*8,+8), [l8*8+64,+8), 128+l8
    float wA[17], wE[17];
    {
        float4 a = *(const float4*)&wdA[lane8 * 8];
        float4 bq = *(const float4*)&wdA[lane8 * 8 + 4];
        float4 cq4 = *(const float4*)&wdA[lane8 * 8 + 64];
        float4 d4 = *(const float4*)&wdA[lane8 * 8 + 68];
        wA[0]=a.x; wA[1]=a.y; wA[2]=a.z; wA[3]=a.w;
        wA[4]=bq.x; wA[5]=bq.y; wA[6]=bq.z; wA[7]=bq.w;
        wA[8]=cq4.x; wA[9]=cq4.y; wA[10]=cq4.z; wA[11]=cq4.w;
        wA[12]=d4.x; wA[13]=d4.y; wA[14]=d4.z; wA[15]=d4.w;
        wA[16]=wdA[128 + lane8];
        if (DIAG) {
            float4 e4 = *(const float4*)&wdE[lane8 * 8];
            float4 f4 = *(const float4*)&wdE[lane8 * 8 + 4];
            float4 g4 = *(const float4*)&wdE[lane8 * 8 + 64];
            float4 h4 = *(const float4*)&wdE[lane8 * 8 + 68];
            wE[0]=e4.x; wE[1]=e4.y; wE[2]=e4.z; wE[3]=e4.w;
            wE[4]=f4.x; wE[5]=f4.y; wE[6]=f4.z; wE[7]=f4.w;
            wE[8]=g4.x; wE[9]=g4.y; wE[10]=g4.z; wE[11]=g4.w;
            wE[12]=h4.x; wE[13]=h4.y; wE[14]=h4.z; wE[15]=h4.w;
            wE[16]=wdE[128 + lane8];
        }
    }

    auto proc = [&](float s, float w, float w2) {
        float pe = __builtin_amdgcn_exp2f(fmaf(CB, s, CA * s * s));
        float rr = __builtin_amdgcn_exp2f(CR * s);
        float sm1 = s - 1.0f;
        float e0 = __builtin_amdgcn_exp2f(C0 * (sm1 * sm1));
        a0[0] = fmaf(w, e0, a0[0]);
        if (DIAG) a2[0] = fmaf(w2, e0, a2[0]);
        float p = pe;
        #pragma unroll
        for (int k = 1; k < KK; k++) {
            a0[k] = fmaf(w, p, a0[k]);
            if (DIAG) a2[k] = fmaf(w2, p, a2[k]);
            p *= rr;
        }
    };

    if (live) {
        const unsigned short* Srow = Sg + (size_t)pair * SR * SD + (size_t)row * SD;
        #pragma unroll
        for (int j = 0; j < 2; j++) {
            uint4 v = *(const uint4*)(Srow + lane8 * 8 + j * 64);
            float sv[8];
            sv[0] = bf2f(v.x & 0xFFFFu); sv[1] = bf2f(v.x >> 16);
            sv[2] = bf2f(v.y & 0xFFFFu); sv[3] = bf2f(v.y >> 16);
            sv[4] = bf2f(v.z & 0xFFFFu); sv[5] = bf2f(v.z >> 16);
            sv[6] = bf2f(v.w & 0xFFFFu); sv[7] = bf2f(v.w >> 16);
            #pragma unroll
            for (int m = 0; m < 8; m++)
                proc(sv[m], wA[j * 8 + m], DIAG ? wE[j * 8 + m] : 0.0f);
        }
        proc(bf2f((unsigned int)Srow[128 + lane8]), wA[16], DIAG ? wE[16] : 0.0f);
    }
    // butterfly over the 8 lanes of each row -> all 8 lanes hold full sums
    #pragma unroll
    for (int k = 0; k < KK; k++) {
        a0[k] += __shfl_xor(a0[k], 1, 64);
        a0[k] += __shfl_xor(a0[k], 2, 64);
        a0[k] += __shfl_xor(a0[k], 4, 64);
        if (DIAG) {
            a2[k] += __shfl_xor(a2[k], 1, 64);
            a2[k] += __shfl_xor(a2[k], 2, 64);
            a2[k] += __shfl_xor(a2[k], 4, 64);
        }
    }
    // distributed log epilogue: lane l8 handles k = l8, l8+8, l8+16
    // WaL/WsL hold W * ln2, so v_log_f32 (log2) yields natural-log dot product.
    float psc = 0.0f, pcq = 0.0f;
    #pragma unroll
    for (int t = 0; t < 3; t++) {
        int k = lane8 + t * 8;
        if (k < KK) {
            psc += WaL[k] * __builtin_amdgcn_logf(fmaxf(CkL[k] * a0[k], 1e-10f));
            if (DIAG) pcq += WsL[k] * __builtin_amdgcn_logf(fmaxf(CkL[k] * a2[k], 1e-10f));
        }
    }
    psc += __shfl_xor(psc, 1, 64);
    psc += __shfl_xor(psc, 2, 64);
    psc += __shfl_xor(psc, 4, 64);
    if (DIAG) {
        pcq += __shfl_xor(pcq, 1, 64);
        pcq += __shfl_xor(pcq, 2, 64);
        pcq += __shfl_xor(pcq, 4, 64);
    }
    float selv = 0.0f, denv = 0.0f;
    if (live && lane8 == 0) {
        score[(size_t)pair * LP + row] = batt[0] + psc;
        if (DIAG) {
            selv = wqC[row] * pcq;
            denv = wqC[row];
        }
    }
    if (DIAG) {
        #pragma unroll
        for (int m = 8; m < 64; m <<= 1) {
            selv += __shfl_xor(selv, m, 64);
            denv += __shfl_xor(denv, m, 64);
        }
        int wave = tid >> 6, lane = tid & 63;
        if (lane == 0) { redsel[wave] = selv; redden[wave] = denv; }
        __syncthreads();
        if (tid == 0) {
            selp[ne * 5 + c] = redsel[0] + redsel[1] + redsel[2] + redsel[3];
            denp[ne * 5 + c] = redden[0] + redden[1] + redden[2] + redden[3];
        }
    }
}

__global__ __launch_bounds__(256) void k_pool(const unsigned short* __restrict__ Sg,
        const int* __restrict__ msk, const int* __restrict__ seg,
        const float* __restrict__ Watt, const float* __restrict__ batt,
        const float* __restrict__ Wsel,
        float* __restrict__ score, float* __restrict__ selp, float* __restrict__ denp) {
    __shared__ __align__(16) float wdA[SD];
    __shared__ __align__(16) float wdE[SD];
    __shared__ __align__(16) float wqC[SD];
    __shared__ float WaL[KK], WsL[KK], CkL[KK];
    __shared__ float redsel[4], redden[4];
    int w = blockIdx.x;                       // 4000 = 8 * 500
    int xcd = w & 7, slot = w >> 3;
    int b = xcd * 4 + (slot / 125);
    int rem = slot % 125;
    int ei = rem / 5, c = rem % 5;
    int e = ei / 5, i = ei % 5;
    int pair = b * 25 + ei;
    int ne = b * 5 + e, ni = b * 5 + i;
    int tid = threadIdx.x;

    if (tid < SD) {
        int d = tid;
        wdA[d] = (d >= 1 && d < LL) ? (float)msk[ni * LL + d] : 0.0f;
        float mtE = (d >= 1 && d < LL) ? (float)msk[ne * LL + d] : 0.0f;
        float sgE = (d < LL) ? (float)seg[ne * LL + d] : 0.0f;
        wdE[d] = sgE * mtE;
        wqC[d] = (1.0f - sgE) * mtE;
    }
    if (tid < KK) {
        const float LOG2E = 1.4426950408889634f;
        const float LN2 = 0.6931471805599453f;
        WaL[tid] = Watt[tid] * LN2;            // ln2 folded: v_log_f32 is log2
        WsL[tid] = Wsel[tid] * LN2;
        float mu = 0.95f - 0.1f * (tid - 1);
        CkL[tid] = (tid == 0) ? 1.0f : __builtin_amdgcn_exp2f(-50.0f * LOG2E * mu * mu);
    }
    __syncthreads();

    int row = c * 26 + (tid >> 3);
    int lane8 = tid & 7;
    bool live = (tid < 208);               // 26 rows * 8 lanes

    if (e == i)
        pool_body<true>(pair, row, lane8, live, ne, c, Sg, batt, score, selp, denp,
                        wdA, wdE, wqC, WaL, WsL, CkL, redsel, redden);
    else
        pool_body<false>(pair, row, lane8, live, ne, c, Sg, batt, score, selp, denp,
                         wdA, wdE, wqC, WaL, WsL, CkL, redsel, redden);
}

// ---------------------------------------------------------------------------
// K4 (fused att+den): grid 480 (be, j). Phase 1: waves compute the 5 masked
// softmaxes into LDS (wave w handles i = w, w+4). Phase 2: denoise chunk j.
// ---------------------------------------------------------------------------
__global__ __launch_bounds__(256) void k_attden(const float* __restrict__ score,
        const int* __restrict__ msk, const float* __restrict__ hid,
        float* __restrict__ dn, unsigned short* __restrict__ xg) {
    int bid = blockIdx.x;
    int be = bid / 3, j = bid % 3;
    int b = be / 5, e = be % 5;
    int tid = threadIdx.x, lane = tid & 63, wave = tid >> 6;
    __shared__ float attl[5 * 132];

    for (int i = wave; i < 5; i += 4) {
        const float* srow = score + ((size_t)(b * 5 + i) * 5 + e) * LP;
        float v0, v1, v2 = -1e30f;
        {
            int q = lane;
            bool mt = (q >= 1 && msk[be * LL + q] != 0);
            v0 = mt ? srow[q] : -1e4f;
        }
        {
            int q = lane + 64;
            bool mt = (msk[be * LL + q] != 0);
            v1 = mt ? srow[q] : -1e4f;
        }
        if (lane < 2) {
            int q = lane + 128;
            bool mt = (msk[be * LL + q] != 0);
            v2 = mt ? srow[q] : -1e4f;
        }
        float mx = fmaxf(v0, fmaxf(v1, v2));
        #pragma unroll
        for (int m = 1; m < 64; m <<= 1) mx = fmaxf(mx, __shfl_xor(mx, m, 64));
        float e0 = __expf(v0 - mx), e1 = __expf(v1 - mx);
        float e2 = (lane < 2) ? __expf(v2 - mx) : 0.0f;
        float Z = e0 + e1 + e2;
        #pragma unroll
        for (int m = 1; m < 64; m <<= 1) Z += __shfl_xor(Z, m, 64);
        float iz = 1.0f / Z;
        attl[i * 132 + lane] = e0 * iz;
        attl[i * 132 + lane + 64] = e1 * iz;
        if (lane < 2) attl[i * 132 + lane + 128] = e2 * iz;
    }
    __syncthreads();

    int h = j * 256 + tid;
    float accA[5] = {0.f, 0.f, 0.f, 0.f, 0.f};
    float accB[5] = {0.f, 0.f, 0.f, 0.f, 0.f};
    const float* hb = hid + (size_t)be * LL * HH + h;
    int q = 0;
    #pragma unroll 2
    for (; q + 4 <= LL; q += 4) {
        float h0 = hb[(size_t)(q + 0) * HH];
        float h1 = hb[(size_t)(q + 1) * HH];
        float h2 = hb[(size_t)(q + 2) * HH];
        float h3 = hb[(size_t)(q + 3) * HH];
        #pragma unroll
        for (int i = 0; i < 5; i++) {
            accA[i] = fmaf(attl[i * 132 + q], h0, accA[i]);
            accB[i] = fmaf(attl[i * 132 + q + 1], h1, accB[i]);
            accA[i] = fmaf(attl[i * 132 + q + 2], h2, accA[i]);
            accB[i] = fmaf(attl[i * 132 + q + 3], h3, accB[i]);
        }
    }
    for (; q < LL; q++) {
        float hv = hb[(size_t)q * HH];
        #pragma unroll
        for (int i = 0; i < 5; i++) accA[i] = fmaf(attl[i * 132 + q], hv, accA[i]);
    }
    #pragma unroll
    for (int i = 0; i < 5; i++) {
        float v = accA[i] + accB[i];
        dn[((size_t)be * 5 + i) * HH + h] = v;
        xg[((size_t)(b * 5 + i) * 5 + e) * 1536 + HH + h] = f2bf(v);
    }
}

// ---------------------------------------------------------------------------
// K5: gating GEMM Cg[800][128] += Xg[800][1536] @ Wg1^T, 3-way K-split,
// f32 atomics into prologue-zeroed cg. grid 150: bid = rb*3 + ks.
// ---------------------------------------------------------------------------
__global__ __launch_bounds__(256) void k_gate_gemm(const unsigned short* __restrict__ xg,
        const unsigned short* __restrict__ wg1b, float* __restrict__ cg) {
    int bid = blockIdx.x;
    int rb = bid / 3, ks = bid % 3;
    int m0 = rb * 16;
    __shared__ unsigned short As[16 * 32];
    __shared__ unsigned short Bs[128 * 32];
    int tid = threadIdx.x, lane = tid & 63, wave = tid >> 6;
    int quad = lane >> 4, l16 = lane & 15;
    f32x4 acc[2];
    acc[0] = (f32x4){0.f, 0.f, 0.f, 0.f};
    acc[1] = (f32x4){0.f, 0.f, 0.f, 0.f};

    for (int t = 0; t < 16; t++) {
        int k0 = ks * 512 + t * 32;
        if (tid < 64) {
            int row = tid >> 2, sg = tid & 3;
            *(uint4*)&As[tid * 8] = *(const uint4*)(xg + (size_t)(m0 + row) * 1536 + k0 + sg * 8);
        }
        #pragma unroll
        for (int it = 0; it < 2; it++) {
            int s = tid + it * 256;
            int row = s >> 2, sg = s & 3;
            *(uint4*)&Bs[s * 8] = *(const uint4*)(wg1b + (size_t)row * 1536 + k0 + sg * 8);
        }
        __syncthreads();
        bf16x8 af = *(const bf16x8*)&As[l16 * 32 + quad * 8];
        #pragma unroll
        for (int nt = 0; nt < 2; nt++) {
            int ct = wave * 2 + nt;
            bf16x8 bfr = *(const bf16x8*)&Bs[(ct * 16 + l16) * 32 + quad * 8];
            acc[nt] = __builtin_amdgcn_mfma_f32_16x16x32_bf16(af, bfr, acc[nt], 0, 0, 0);
        }
        __syncthreads();
    }
    #pragma unroll
    for (int nt = 0; nt < 2; nt++) {
        int C = (wave * 2 + nt) * 16 + l16;
        #pragma unroll
        for (int reg = 0; reg < 4; reg++) {
            int R = m0 + quad * 4 + reg;
            atomicAdd(&cg[(size_t)R * 128 + C], acc[nt][reg]);
        }
    }
}

// ---------------------------------------------------------------------------
// K6: per (b,i): g[e] = Wg2.relu(cg+bg1)+bg2; softmax_e; de; feat = Wd.concat
// ---------------------------------------------------------------------------
__global__ __launch_bounds__(256) void k_gate_epi(const float* __restrict__ cg,
        const float* __restrict__ bg1, const float* __restrict__ wg2,
        const float* __restrict__ bg2, const float* __restrict__ dn,
        const float* __restrict__ pooled, const float* __restrict__ wd,
        const float* __restrict__ bd, float* __restrict__ feat) {
    int bi = blockIdx.x;                 // b*5+i
    int b = bi / 5, ii = bi % 5;
    __shared__ float red4[4];
    __shared__ float gL[5];
    __shared__ float deL[HH];
    int tid = threadIdx.x, lane = tid & 63, wave = tid >> 6;

    for (int e = 0; e < 5; e++) {
        float v = 0.0f;
        if (tid < 128) {
            float ccv = cg[(size_t)(bi * 5 + e) * 128 + tid] + bg1[tid];
            v = wg2[tid] * fmaxf(ccv, 0.0f);
        }
        #pragma unroll
        for (int m = 1; m < 64; m <<= 1) v += __shfl_xor(v, m, 64);
        if (lane == 0) red4[wave] = v;
        __syncthreads();
        if (tid == 0) gL[e] = red4[0] + red4[1] + bg2[0];
        __syncthreads();
    }
    float mx = gL[0];
    #pragma unroll
    for (int e = 1; e < 5; e++) mx = fmaxf(mx, gL[e]);
    float wde[5]; float z = 0.0f;
    #pragma unroll
    for (int e = 0; e < 5; e++) { wde[e] = __expf(gL[e] - mx); z += wde[e]; }
    float iz = 1.0f / z;
    #pragma unroll
    for (int e = 0; e < 5; e++) wde[e] *= iz;

    #pragma unroll
    for (int j = 0; j < 3; j++) {
        int h = tid + j * 256;
        float v = 0.0f;
        #pragma unroll
        for (int e = 0; e < 5; e++)
            v += wde[e] * dn[((size_t)(b * 5 + e) * 5 + ii) * HH + h];
        deL[h] = v;
    }
    __syncthreads();

    float part[3] = {0.0f, 0.0f, 0.0f};
    #pragma unroll
    for (int mm = 0; mm < 6; mm++) {
        int h = tid + mm * 256;
        float x = (mm < 3) ? pooled[(size_t)bi * HH + h] : deL[h - HH];
        #pragma unroll
        for (int c = 0; c < 3; c++) part[c] = fmaf(x, wd[(size_t)c * 1536 + h], part[c]);
    }
    #pragma unroll
    for (int c = 0; c < 3; c++) {
        float v = part[c];
        #pragma unroll
        for (int m = 1; m < 64; m <<= 1) v += __shfl_xor(v, m, 64);
        if (lane == 0) red4[wave] = v;
        __syncthreads();
        if (tid == 0) feat[bi * 3 + c] = red4[0] + red4[1] + red4[2] + red4[3] + bd[c];
        __syncthreads();
    }
}

// ---------------------------------------------------------------------------
// K7: final: sel from partials, select softmax over i, class softmax, log
// ---------------------------------------------------------------------------
__global__ __launch_bounds__(64) void k_final(const float* __restrict__ selp,
        const float* __restrict__ denp, const float* __restrict__ bsel,
        const float* __restrict__ feat, float* __restrict__ out) {
    int b = threadIdx.x;
    if (b >= BB) return;
    float sv[5]; float m = -1e30f;
    #pragma unroll
    for (int i = 0; i < 5; i++) {
        float num = 0.0f, den = 0.0f;
        #pragma unroll
        for (int c = 0; c < 5; c++) {
            num += selp[(b * 5 + i) * 5 + c];
            den += denp[(b * 5 + i) * 5 + c];
        }
        sv[i] = bsel[0] + num / (den + 1e-10f);
        m = fmaxf(m, sv[i]);
    }
    float z = 0.0f;
    #pragma unroll
    for (int i = 0; i < 5; i++) { sv[i] = __expf(sv[i] - m); z += sv[i]; }
    #pragma unroll
    for (int i = 0; i < 5; i++) sv[i] /= z;
    float prob[3] = {0.0f, 0.0f, 0.0f};
    #pragma unroll
    for (int i = 0; i < 5; i++) {
        float f0 = feat[(b * 5 + i) * 3 + 0];
        float f1 = feat[(b * 5 + i) * 3 + 1];
        float f2 = feat[(b * 5 + i) * 3 + 2];
        float mm = fmaxf(f0, fmaxf(f1, f2));
        float e0 = __expf(f0 - mm), e1 = __expf(f1 - mm), e2 = __expf(f2 - mm);
        float zz = e0 + e1 + e2;
        prob[0] += sv[i] * e0 / zz;
        prob[1] += sv[i] * e1 / zz;
        prob[2] += sv[i] * e2 / zz;
    }
    #pragma unroll
    for (int c = 0; c < 3; c++) out[b * 3 + c] = __logf(prob[c]);
}

// ---------------------------------------------------------------------------
extern "C" void kernel_launch(void* const* d_in, const int* in_sizes, int n_in,
                              void* d_out, int out_size, void* d_ws, size_t ws_size,
                              hipStream_t stream) {
    const float* hiddens = (const float*)d_in[0];
    const float* pooled  = (const float*)d_in[1];
    const int*   msk     = (const int*)d_in[2];
    const int*   seg     = (const int*)d_in[3];
    const float* Watt    = (const float*)d_in[4];
    const float* batt    = (const float*)d_in[5];
    const float* Wsel    = (const float*)d_in[6];
    const float* bsel    = (const float*)d_in[7];
    const float* Wg1     = (const float*)d_in[8];
    const float* bg1     = (const float*)d_in[9];
    const float* Wg2     = (const float*)d_in[10];
    const float* bg2     = (const float*)d_in[11];
    const float* Wd      = (const float*)d_in[12];
    const float* bd      = (const float*)d_in[13];

    char* ws = (char*)d_ws;
    size_t off = 0;
    auto alloc = [&](size_t bytes) -> void* {
        void* p = ws + off;
        off += (bytes + 255) & ~(size_t)255;
        return p;
    };
    unsigned short* hnbf   = (unsigned short*)alloc((size_t)160 * LL * HH * 2);  // 31.9 MB
    unsigned short* Sg     = (unsigned short*)alloc((size_t)800 * SR * SD * 2);  // 28.3 MB
    float*          score  = (float*)alloc((size_t)800 * LP * 4);
    float*          selp   = (float*)alloc((size_t)160 * 5 * 4);
    float*          denp   = (float*)alloc((size_t)160 * 5 * 4);
    float*          dn     = (float*)alloc((size_t)160 * 5 * HH * 4);            // 2.46 MB
    unsigned short* xg     = (unsigned short*)alloc((size_t)800 * 1536 * 2);
    unsigned short* wg1b   = (unsigned short*)alloc((size_t)128 * 1536 * 2);
    float*          cg     = (float*)alloc((size_t)800 * 128 * 4);
    float*          feat   = (float*)alloc((size_t)800 * 3 * 4);
    (void)ws_size; (void)in_sizes; (void)n_in; (void)out_size;

    k_prologue<<<dim3(6868), dim3(256), 0, stream>>>(hiddens, hnbf, Wg1, wg1b, pooled, xg, cg);
    k_sim_gemm<<<dim3(800), dim3(256), 0, stream>>>(hnbf, Sg);
    k_pool<<<dim3(4000), dim3(256), 0, stream>>>(Sg, msk, seg, Watt, batt, Wsel, score, selp, denp);
    k_attden<<<dim3(480), dim3(256), 0, stream>>>(score, msk, hiddens, dn, xg);
    k_gate_gemm<<<dim3(150), dim3(256), 0, stream>>>(xg, wg1b, cg);
    k_gate_epi<<<dim3(160), dim3(256), 0, stream>>>(cg, bg1, Wg2, bg2, dn, pooled, Wd, bd, feat);
    k_final<<<dim3(1), dim3(64), 0, stream>>>(selp, denp, bsel, feat, (float*)d_out);
}